// Round 14
// baseline (926.694 us; speedup 1.0000x reference)
//
#include <hip/hip_runtime.h>
#include <hip/hip_bf16.h>

// Single-CU-autonomous LSTM: 128 blocks x 512 threads, BC=16 batches/block.
// Full W_hh (1024x256 bf16 = 512 KB) per block: 6/8 tiles per wave in the
// unified VGPR/AGPR file (384 KB), 2/8 tiles in LDS (128 KB). One barrier
// per step (r8 structure). vs r8, two register-neutral micro-opts only:
//  - gate rows pre-scaled at PACK time by -log2e (i,f,o) / +2log2e (g):
//    every transcendental is a bare v_exp (exp2), no per-gate mul
//    (numerics verified by r13's passing absmax).
//  - the x/bias fold MFMAs run at the TOP of the step as acc-initializers
//    (reading wxb from LDS per step, NOT hoisted — r10's remat lesson),
//    overlapping the first bfr-load latency instead of forming a tail.
// h-pack stays hand-rolled f2bf: r13's cvt_pk inline asm pinned values to
// arch-VGPRs and spilled (FETCH/WRITE ballooned) — never again at 256/lane.

#define TT 256
#define HH 256
#define BC 16
#define NTH 512

typedef __attribute__((ext_vector_type(8))) short short8;
typedef __attribute__((ext_vector_type(4))) float floatx4;

__device__ __forceinline__ unsigned short f2bf(float f) {
    union { float f; unsigned u; } v; v.f = f;
    unsigned r = v.u + 0x7FFFu + ((v.u >> 16) & 1u);   // RNE, finite inputs only
    return (unsigned short)(r >> 16);
}
// sigmoid(p) with acc = -log2e * p:   rcp(1 + 2^acc)
__device__ __forceinline__ float sig2(float a) {
    return __builtin_amdgcn_rcpf(1.f + exp2f(a));
}
// tanh(p) with acc = +2log2e * p:     1 - 2*rcp(2^acc + 1)
__device__ __forceinline__ float tanh2(float a) {
    return fmaf(-2.f, __builtin_amdgcn_rcpf(exp2f(a) + 1.f), 1.f);
}

__global__ __attribute__((amdgpu_flat_work_group_size(512, 512),
                          amdgpu_waves_per_eu(2, 2)))
void lstm_onecu(
    const float* __restrict__ y_hist, const float* __restrict__ h0,
    const float* __restrict__ c0, const float* __restrict__ W_ih,
    const float* __restrict__ W_hh, const float* __restrict__ b_ih,
    const float* __restrict__ b_hh, const float* __restrict__ W_fc,
    const float* __restrict__ b_fc, float* __restrict__ out)
{
    // LDS budget (160 KB): W tiles 128K + h ping-pong 16K + x 8K + wxb 4K
    __shared__ __align__(16) char  WLDS[131072];   // [w][ti][s][lane] 16B frags
    __shared__ __align__(16) char  hb[2][8192];    // [b 16][hid 256] bf16, swz
    __shared__ unsigned short xw[TT * BC];         // bf16(x) [t][b]
    __shared__ unsigned wxb[8 * 8 * 16];           // {bias|wx} per (w,tau,lr)
    __shared__ float outacc[BC * 2];

    const int tid = threadIdx.x;
    const int w   = tid >> 6;        // wave 0..7: owns hidden [32w, 32w+32)
    const int l   = tid & 63;
    const int lr  = l & 15;          // batch lane (B/D col); A-row lane
    const int lg  = l >> 4;          // k-group 0..3
    const int b0  = blockIdx.x * BC;

    // gate-row scales: i,f,o -> -log2e (sigmoid); g -> +2log2e (tanh)
    const float SCL[4] = {-1.44269504089f, -1.44269504089f,
                           2.88539008178f, -1.44269504089f};

    // ---- stage x -> bf16 [t][b] ----
    for (int idx = tid; idx < TT * BC; idx += NTH) {
        int bb = idx >> 8, t = idx & 255;
        xw[t * BC + bb] = f2bf(y_hist[(size_t)(b0 + bb) * TT + t]);
    }
    // ---- stage h0 -> bf16 swizzled LDS buf0 ----
    for (int idx = tid; idx < BC * 128; idx += NTH) {
        int bb = idx >> 7, d = idx & 127;
        const float* hp = &h0[(size_t)(b0 + bb) * HH + 2 * d];
        unsigned val = (unsigned)f2bf(hp[0]) | ((unsigned)f2bf(hp[1]) << 16);
        *(unsigned*)(hb[0] + bb * 512 + ((d * 4) ^ ((bb & 7) << 4))) = val;
    }
    if (tid < BC * 2) outacc[tid] = 0.f;

    // ---- c state: lane owns (batch lr, units 32w+16ch+4lg+r) ----
    float cc[2][4];
#pragma unroll
    for (int ch = 0; ch < 2; ++ch)
#pragma unroll
        for (int r = 0; r < 4; ++r)
            cc[ch][r] = c0[(size_t)(b0 + lr) * HH + 32 * w + 16 * ch + 4 * lg + r];

    // ---- W tiles (pre-scaled): tau = ch*4+gt; reg tau 0..5, LDS tau 6,7 ----
    short8 wfrag[48];
#pragma unroll
    for (int tau = 0; tau < 6; ++tau) {
        const int gt = tau & 3, ch = tau >> 2;
        const int row = 256 * gt + 32 * w + 16 * ch + lr;
        const float sc = SCL[gt];
#pragma unroll
        for (int s = 0; s < 8; ++s) {
            const float* p = &W_hh[(size_t)row * HH + 8 * lg + 32 * s];
            short8 f;
#pragma unroll
            for (int i = 0; i < 8; ++i) f[i] = (short)f2bf(sc * p[i]);
            wfrag[tau * 8 + s] = f;
        }
    }
#pragma unroll
    for (int i = 0; i < 48; ++i)
        asm volatile("" : "+v"(wfrag[i]));

#pragma unroll
    for (int ti = 0; ti < 2; ++ti) {                 // tau 6,7: ch=1, gt=2+ti
        const int gt = 2 + ti;
        const int row = 256 * gt + 32 * w + 16 + lr;
        const float sc = SCL[gt];
#pragma unroll
        for (int s = 0; s < 8; ++s) {
            const float* p = &W_hh[(size_t)row * HH + 8 * lg + 32 * s];
            short8 f;
#pragma unroll
            for (int i = 0; i < 8; ++i) f[i] = (short)f2bf(sc * p[i]);
            *(short8*)(WLDS + w * 16384 + ti * 8192 + s * 1024 + l * 16) = f;
        }
    }
    // ---- wxb (pre-scaled): per (w, tau, row=lr): lo16 = wx, hi16 = bias ----
#pragma unroll
    for (int tau = 0; tau < 8; ++tau) {
        const int gt = tau & 3, ch = tau >> 2;
        const int row = 256 * gt + 32 * w + 16 * ch + lr;
        const float sc = SCL[gt];
        if (lg == 0)
            wxb[w * 128 + tau * 16 + lr] =
                (unsigned)f2bf(sc * W_ih[row]) |
                ((unsigned)f2bf(sc * (b_ih[row] + b_hh[row])) << 16);
    }

    __syncthreads();

    const unsigned sw  = (unsigned)((lr & 7) << 4);
    const unsigned rdb = (unsigned)(lr * 512);
    const unsigned cwb = (unsigned)(64 * w + 8 * lg);   // write col base
    const char* wbase = WLDS + w * 16384 + l * 16;
    const float C2S = 2.88539008178f;                   // 2*log2e for tanh(c)
    const floatx4 zf = {0.f, 0.f, 0.f, 0.f};
    float hv[2][4];

#pragma unroll 1
    for (int t = 0; t < TT; ++t) {
        const char* rb = hb[t & 1];
        char* wbp = hb[(t + 1) & 1];

        // ---- fold as acc-init (wxb from LDS, per step — overlaps bfr lat) ----
        unsigned xword = (lg == 0)
            ? ((0x3F80u << 16) | (unsigned)xw[t * BC + lr]) : 0u;
        short8 b8 = {(short)(xword & 0xFFFF), (short)(xword >> 16),
                     0, 0, 0, 0, 0, 0};
        floatx4 acc[8];
#pragma unroll
        for (int tau = 0; tau < 8; ++tau) {
            unsigned wv = (lg == 0) ? wxb[w * 128 + tau * 16 + lr] : 0u;
            short8 a8 = {(short)(wv & 0xFFFF), (short)(wv >> 16),
                         0, 0, 0, 0, 0, 0};
            acc[tau] = __builtin_amdgcn_mfma_f32_16x16x32_bf16(
                           a8, b8, zf, 0, 0, 0);
        }

        // ---- K loop: r8 rhythm, 3 loads then 8 MFMAs per s ----
#pragma unroll
        for (int s = 0; s < 8; ++s) {
            short8 w6 = *(const short8*)(wbase + s * 1024);
            short8 w7 = *(const short8*)(wbase + 8192 + s * 1024);
            short8 bfr = *(const short8*)(rb + rdb +
                             (((unsigned)(16 * lg + 64 * s)) ^ sw));
#pragma unroll
            for (int tau = 0; tau < 6; ++tau)
                acc[tau] = __builtin_amdgcn_mfma_f32_16x16x32_bf16(
                               wfrag[tau * 8 + s], bfr, acc[tau], 0, 0, 0);
            acc[6] = __builtin_amdgcn_mfma_f32_16x16x32_bf16(
                         w6, bfr, acc[6], 0, 0, 0);
            acc[7] = __builtin_amdgcn_mfma_f32_16x16x32_bf16(
                         w7, bfr, acc[7], 0, 0, 0);
        }

        // ---- gates -> c,h (pre-scaled accs: bare exp2) ----
#pragma unroll
        for (int ch = 0; ch < 2; ++ch) {
#pragma unroll
            for (int r = 0; r < 4; ++r) {
                float iv = sig2(acc[ch * 4 + 0][r]);
                float fv = sig2(acc[ch * 4 + 1][r]);
                float gv = tanh2(acc[ch * 4 + 2][r]);
                float ov = sig2(acc[ch * 4 + 3][r]);
                float c2 = fmaf(fv, cc[ch][r], iv * gv);
                cc[ch][r] = c2;
                hv[ch][r] = ov * tanh2(C2S * c2);
            }
            unsigned lo = (unsigned)f2bf(hv[ch][0]) |
                          ((unsigned)f2bf(hv[ch][1]) << 16);
            unsigned hi = (unsigned)f2bf(hv[ch][2]) |
                          ((unsigned)f2bf(hv[ch][3]) << 16);
            uint2 pk; pk.x = lo; pk.y = hi;
            *(uint2*)(wbp + rdb + (((unsigned)(cwb + 32 * ch)) ^ sw)) = pk;
        }

        __syncthreads();
    }

    // ---- epilogue: out = h_T @ W_fc^T + b_fc (block owns its batches) ----
    float p0 = 0.f, p1 = 0.f;
#pragma unroll
    for (int ch = 0; ch < 2; ++ch)
#pragma unroll
        for (int r = 0; r < 4; ++r) {
            const int u = 32 * w + 16 * ch + 4 * lg + r;
            p0 = fmaf(hv[ch][r], W_fc[u],      p0);
            p1 = fmaf(hv[ch][r], W_fc[HH + u], p1);
        }
    p0 += __shfl_xor(p0, 16, 64); p0 += __shfl_xor(p0, 32, 64);
    p1 += __shfl_xor(p1, 16, 64); p1 += __shfl_xor(p1, 32, 64);
    if (lg == 0) {
        atomicAdd(&outacc[lr * 2 + 0], p0);
        atomicAdd(&outacc[lr * 2 + 1], p1);
    }
    __syncthreads();
    if (tid < BC * 2) {
        int bb = tid >> 1, o = tid & 1;
        out[(size_t)(b0 + bb) * 2 + o] = outacc[tid] + b_fc[o];
    }
}

extern "C" void kernel_launch(void* const* d_in, const int* in_sizes, int n_in,
                              void* d_out, int out_size, void* d_ws, size_t ws_size,
                              hipStream_t stream) {
    const float* y_hist = (const float*)d_in[0];
    const float* h0     = (const float*)d_in[1];
    const float* c0     = (const float*)d_in[2];
    const float* W_ih   = (const float*)d_in[3];
    const float* W_hh   = (const float*)d_in[4];
    const float* b_ih   = (const float*)d_in[5];
    const float* b_hh   = (const float*)d_in[6];
    const float* W_fc   = (const float*)d_in[7];
    const float* b_fc   = (const float*)d_in[8];

    lstm_onecu<<<2048 / BC, NTH, 0, stream>>>(
        y_hist, h0, c0, W_ih, W_hh, b_ih, b_hh, W_fc, b_fc, (float*)d_out);
}

// Round 15
// 866.720 us; speedup vs baseline: 1.0692x; 1.0692x over previous
//
#include <hip/hip_runtime.h>
#include <hip/hip_bf16.h>

// Single-CU-autonomous LSTM: 128 blocks x 512 threads, BC=16 batches/block.
// Full W_hh (1024x256 bf16 = 512 KB) per block: 6/8 tiles per wave in the
// unified VGPR/AGPR file (384 KB), 2/8 tiles in LDS (128 KB). EXACT r8
// structure (fold as END tail reading wxb from LDS; one barrier per step;
// hand-rolled f2bf pack; 3-load -> 8-MFMA rhythm). Single change vs r8:
// gate rows pre-scaled at PACK time (i,f,o: -log2e; g: +2log2e) so each
// transcendental is a bare v_exp (exp2) with no per-gate multiply.
// All other r8 perturbations (fold-at-top, hoisting, batching, L2-stream,
// flags, cvt_pk asm) regressed -- the r8 schedule is saturated at 256
// regs/lane and tolerates no added register pressure.

#define TT 256
#define HH 256
#define BC 16
#define NTH 512

typedef __attribute__((ext_vector_type(8))) short short8;
typedef __attribute__((ext_vector_type(4))) float floatx4;

__device__ __forceinline__ unsigned short f2bf(float f) {
    union { float f; unsigned u; } v; v.f = f;
    unsigned r = v.u + 0x7FFFu + ((v.u >> 16) & 1u);   // RNE, finite inputs only
    return (unsigned short)(r >> 16);
}
// sigmoid(p) with acc = -log2e * p:   rcp(1 + 2^acc)
__device__ __forceinline__ float sig2(float a) {
    return __builtin_amdgcn_rcpf(1.f + exp2f(a));
}
// tanh(p) with acc = +2log2e * p:     1 - 2*rcp(2^acc + 1)
__device__ __forceinline__ float tanh2(float a) {
    return fmaf(-2.f, __builtin_amdgcn_rcpf(exp2f(a) + 1.f), 1.f);
}

__global__ __attribute__((amdgpu_flat_work_group_size(512, 512),
                          amdgpu_waves_per_eu(2, 2)))
void lstm_onecu(
    const float* __restrict__ y_hist, const float* __restrict__ h0,
    const float* __restrict__ c0, const float* __restrict__ W_ih,
    const float* __restrict__ W_hh, const float* __restrict__ b_ih,
    const float* __restrict__ b_hh, const float* __restrict__ W_fc,
    const float* __restrict__ b_fc, float* __restrict__ out)
{
    // LDS budget (160 KB): W tiles 128K + h ping-pong 16K + x 8K + wxb 4K
    __shared__ __align__(16) char  WLDS[131072];   // [w][ti][s][lane] 16B frags
    __shared__ __align__(16) char  hb[2][8192];    // [b 16][hid 256] bf16, swz
    __shared__ unsigned short xw[TT * BC];         // bf16(x) [t][b]
    __shared__ unsigned wxb[8 * 8 * 16];           // {bias|wx} per (w,tau,lr)
    __shared__ float outacc[BC * 2];

    const int tid = threadIdx.x;
    const int w   = tid >> 6;        // wave 0..7: owns hidden [32w, 32w+32)
    const int l   = tid & 63;
    const int lr  = l & 15;          // batch lane (B/D col); A-row lane
    const int lg  = l >> 4;          // k-group 0..3
    const int b0  = blockIdx.x * BC;

    // gate-row scales: i,f,o -> -log2e (sigmoid); g -> +2log2e (tanh)
    const float SCL[4] = {-1.44269504089f, -1.44269504089f,
                           2.88539008178f, -1.44269504089f};

    // ---- stage x -> bf16 [t][b] ----
    for (int idx = tid; idx < TT * BC; idx += NTH) {
        int bb = idx >> 8, t = idx & 255;
        xw[t * BC + bb] = f2bf(y_hist[(size_t)(b0 + bb) * TT + t]);
    }
    // ---- stage h0 -> bf16 swizzled LDS buf0 ----
    for (int idx = tid; idx < BC * 128; idx += NTH) {
        int bb = idx >> 7, d = idx & 127;
        const float* hp = &h0[(size_t)(b0 + bb) * HH + 2 * d];
        unsigned val = (unsigned)f2bf(hp[0]) | ((unsigned)f2bf(hp[1]) << 16);
        *(unsigned*)(hb[0] + bb * 512 + ((d * 4) ^ ((bb & 7) << 4))) = val;
    }
    if (tid < BC * 2) outacc[tid] = 0.f;

    // ---- c state: lane owns (batch lr, units 32w+16ch+4lg+r) ----
    float cc[2][4];
#pragma unroll
    for (int ch = 0; ch < 2; ++ch)
#pragma unroll
        for (int r = 0; r < 4; ++r)
            cc[ch][r] = c0[(size_t)(b0 + lr) * HH + 32 * w + 16 * ch + 4 * lg + r];

    // ---- W tiles (pre-scaled): tau = ch*4+gt; reg tau 0..5, LDS tau 6,7 ----
    short8 wfrag[48];
#pragma unroll
    for (int tau = 0; tau < 6; ++tau) {
        const int gt = tau & 3, ch = tau >> 2;
        const int row = 256 * gt + 32 * w + 16 * ch + lr;
        const float sc = SCL[gt];
#pragma unroll
        for (int s = 0; s < 8; ++s) {
            const float* p = &W_hh[(size_t)row * HH + 8 * lg + 32 * s];
            short8 f;
#pragma unroll
            for (int i = 0; i < 8; ++i) f[i] = (short)f2bf(sc * p[i]);
            wfrag[tau * 8 + s] = f;
        }
    }
#pragma unroll
    for (int i = 0; i < 48; ++i)
        asm volatile("" : "+v"(wfrag[i]));

#pragma unroll
    for (int ti = 0; ti < 2; ++ti) {                 // tau 6,7: ch=1, gt=2+ti
        const int gt = 2 + ti;
        const int row = 256 * gt + 32 * w + 16 + lr;
        const float sc = SCL[gt];
#pragma unroll
        for (int s = 0; s < 8; ++s) {
            const float* p = &W_hh[(size_t)row * HH + 8 * lg + 32 * s];
            short8 f;
#pragma unroll
            for (int i = 0; i < 8; ++i) f[i] = (short)f2bf(sc * p[i]);
            *(short8*)(WLDS + w * 16384 + ti * 8192 + s * 1024 + l * 16) = f;
        }
    }
    // ---- wxb (pre-scaled): per (w, tau, row=lr): lo16 = wx, hi16 = bias ----
#pragma unroll
    for (int tau = 0; tau < 8; ++tau) {
        const int gt = tau & 3, ch = tau >> 2;
        const int row = 256 * gt + 32 * w + 16 * ch + lr;
        const float sc = SCL[gt];
        if (lg == 0)
            wxb[w * 128 + tau * 16 + lr] =
                (unsigned)f2bf(sc * W_ih[row]) |
                ((unsigned)f2bf(sc * (b_ih[row] + b_hh[row])) << 16);
    }

    __syncthreads();

    const unsigned sw  = (unsigned)((lr & 7) << 4);
    const unsigned rdb = (unsigned)(lr * 512);
    const unsigned cwb = (unsigned)(64 * w + 8 * lg);   // write col base
    const char* wbase = WLDS + w * 16384 + l * 16;
    const float C2S = 2.88539008178f;                   // 2*log2e for tanh(c)
    float hv[2][4];

#pragma unroll 1
    for (int t = 0; t < TT; ++t) {
        const char* rb = hb[t & 1];
        char* wbp = hb[(t + 1) & 1];

        floatx4 acc[8] = {};

        // ---- K loop: r8 rhythm, 3 loads then 8 MFMAs per s ----
#pragma unroll
        for (int s = 0; s < 8; ++s) {
            short8 w6 = *(const short8*)(wbase + s * 1024);
            short8 w7 = *(const short8*)(wbase + 8192 + s * 1024);
            short8 bfr = *(const short8*)(rb + rdb +
                             (((unsigned)(16 * lg + 64 * s)) ^ sw));
#pragma unroll
            for (int tau = 0; tau < 6; ++tau)
                acc[tau] = __builtin_amdgcn_mfma_f32_16x16x32_bf16(
                               wfrag[tau * 8 + s], bfr, acc[tau], 0, 0, 0);
            acc[6] = __builtin_amdgcn_mfma_f32_16x16x32_bf16(
                         w6, bfr, acc[6], 0, 0, 0);
            acc[7] = __builtin_amdgcn_mfma_f32_16x16x32_bf16(
                         w7, bfr, acc[7], 0, 0, 0);
        }

        // ---- 9th K-step (r8 position): [wx | bias] x [x; 1] on lg==0 ----
        {
            unsigned xword = (lg == 0)
                ? ((0x3F80u << 16) | (unsigned)xw[t * BC + lr]) : 0u;
            short8 b8 = {(short)(xword & 0xFFFF), (short)(xword >> 16),
                         0, 0, 0, 0, 0, 0};
#pragma unroll
            for (int tau = 0; tau < 8; ++tau) {
                unsigned wv = (lg == 0) ? wxb[w * 128 + tau * 16 + lr] : 0u;
                short8 a8 = {(short)(wv & 0xFFFF), (short)(wv >> 16),
                             0, 0, 0, 0, 0, 0};
                acc[tau] = __builtin_amdgcn_mfma_f32_16x16x32_bf16(
                               a8, b8, acc[tau], 0, 0, 0);
            }
        }

        // ---- gates -> c,h (pre-scaled accs: bare exp2) ----
#pragma unroll
        for (int ch = 0; ch < 2; ++ch) {
#pragma unroll
            for (int r = 0; r < 4; ++r) {
                float iv = sig2(acc[ch * 4 + 0][r]);
                float fv = sig2(acc[ch * 4 + 1][r]);
                float gv = tanh2(acc[ch * 4 + 2][r]);
                float ov = sig2(acc[ch * 4 + 3][r]);
                float c2 = fmaf(fv, cc[ch][r], iv * gv);
                cc[ch][r] = c2;
                hv[ch][r] = ov * tanh2(C2S * c2);
            }
            unsigned lo = (unsigned)f2bf(hv[ch][0]) |
                          ((unsigned)f2bf(hv[ch][1]) << 16);
            unsigned hi = (unsigned)f2bf(hv[ch][2]) |
                          ((unsigned)f2bf(hv[ch][3]) << 16);
            uint2 pk; pk.x = lo; pk.y = hi;
            *(uint2*)(wbp + rdb + (((unsigned)(cwb + 32 * ch)) ^ sw)) = pk;
        }

        __syncthreads();
    }

    // ---- epilogue: out = h_T @ W_fc^T + b_fc (block owns its batches) ----
    float p0 = 0.f, p1 = 0.f;
#pragma unroll
    for (int ch = 0; ch < 2; ++ch)
#pragma unroll
        for (int r = 0; r < 4; ++r) {
            const int u = 32 * w + 16 * ch + 4 * lg + r;
            p0 = fmaf(hv[ch][r], W_fc[u],      p0);
            p1 = fmaf(hv[ch][r], W_fc[HH + u], p1);
        }
    p0 += __shfl_xor(p0, 16, 64); p0 += __shfl_xor(p0, 32, 64);
    p1 += __shfl_xor(p1, 16, 64); p1 += __shfl_xor(p1, 32, 64);
    if (lg == 0) {
        atomicAdd(&outacc[lr * 2 + 0], p0);
        atomicAdd(&outacc[lr * 2 + 1], p1);
    }
    __syncthreads();
    if (tid < BC * 2) {
        int bb = tid >> 1, o = tid & 1;
        out[(size_t)(b0 + bb) * 2 + o] = outacc[tid] + b_fc[o];
    }
}

extern "C" void kernel_launch(void* const* d_in, const int* in_sizes, int n_in,
                              void* d_out, int out_size, void* d_ws, size_t ws_size,
                              hipStream_t stream) {
    const float* y_hist = (const float*)d_in[0];
    const float* h0     = (const float*)d_in[1];
    const float* c0     = (const float*)d_in[2];
    const float* W_ih   = (const float*)d_in[3];
    const float* W_hh   = (const float*)d_in[4];
    const float* b_ih   = (const float*)d_in[5];
    const float* b_hh   = (const float*)d_in[6];
    const float* W_fc   = (const float*)d_in[7];
    const float* b_fc   = (const float*)d_in[8];

    lstm_onecu<<<2048 / BC, NTH, 0, stream>>>(
        y_hist, h0, c0, W_ih, W_hh, b_ih, b_hh, W_fc, b_fc, (float*)d_out);
}

// Round 16
// 678.898 us; speedup vs baseline: 1.3650x; 1.2767x over previous
//
#include <hip/hip_runtime.h>
#include <hip/hip_bf16.h>

// Single-CU-autonomous LSTM: 128 blocks x 512 threads, BC=16 batches/block.
// Full W_hh (1024x256 bf16 = 512 KB) per block: 6/8 tiles per wave in the
// unified VGPR/AGPR file (384 KB), 2/8 tiles in LDS (128 KB). EXACT r8
// structure. Single change vs r8: gate rows pre-scaled at PACK time
// (i,f,o: -log2e; g: +2log2e) and the transcendental is the RAW
// __builtin_amdgcn_exp2f (bare v_exp_f32). r15 proved plain exp2f() is an
// OCML denormal-safe libcall that spills at our 256-reg/lane razor edge
// (WRITE 15->29.7 MB); the raw builtin has no wrapper and no extra temps.

#define TT 256
#define HH 256
#define BC 16
#define NTH 512

typedef __attribute__((ext_vector_type(8))) short short8;
typedef __attribute__((ext_vector_type(4))) float floatx4;

__device__ __forceinline__ unsigned short f2bf(float f) {
    union { float f; unsigned u; } v; v.f = f;
    unsigned r = v.u + 0x7FFFu + ((v.u >> 16) & 1u);   // RNE, finite inputs only
    return (unsigned short)(r >> 16);
}
// sigmoid(p) with acc = -log2e * p:   rcp(1 + 2^acc)
__device__ __forceinline__ float sig2(float a) {
    return __builtin_amdgcn_rcpf(1.f + __builtin_amdgcn_exp2f(a));
}
// tanh(p) with acc = +2log2e * p:     1 - 2*rcp(2^acc + 1)
__device__ __forceinline__ float tanh2(float a) {
    return fmaf(-2.f, __builtin_amdgcn_rcpf(__builtin_amdgcn_exp2f(a) + 1.f), 1.f);
}

__global__ __attribute__((amdgpu_flat_work_group_size(512, 512),
                          amdgpu_waves_per_eu(2, 2)))
void lstm_onecu(
    const float* __restrict__ y_hist, const float* __restrict__ h0,
    const float* __restrict__ c0, const float* __restrict__ W_ih,
    const float* __restrict__ W_hh, const float* __restrict__ b_ih,
    const float* __restrict__ b_hh, const float* __restrict__ W_fc,
    const float* __restrict__ b_fc, float* __restrict__ out)
{
    // LDS budget (160 KB): W tiles 128K + h ping-pong 16K + x 8K + wxb 4K
    __shared__ __align__(16) char  WLDS[131072];   // [w][ti][s][lane] 16B frags
    __shared__ __align__(16) char  hb[2][8192];    // [b 16][hid 256] bf16, swz
    __shared__ unsigned short xw[TT * BC];         // bf16(x) [t][b]
    __shared__ unsigned wxb[8 * 8 * 16];           // {bias|wx} per (w,tau,lr)
    __shared__ float outacc[BC * 2];

    const int tid = threadIdx.x;
    const int w   = tid >> 6;        // wave 0..7: owns hidden [32w, 32w+32)
    const int l   = tid & 63;
    const int lr  = l & 15;          // batch lane (B/D col); A-row lane
    const int lg  = l >> 4;          // k-group 0..3
    const int b0  = blockIdx.x * BC;

    // gate-row scales: i,f,o -> -log2e (sigmoid); g -> +2log2e (tanh)
    const float SCL[4] = {-1.44269504089f, -1.44269504089f,
                           2.88539008178f, -1.44269504089f};

    // ---- stage x -> bf16 [t][b] ----
    for (int idx = tid; idx < TT * BC; idx += NTH) {
        int bb = idx >> 8, t = idx & 255;
        xw[t * BC + bb] = f2bf(y_hist[(size_t)(b0 + bb) * TT + t]);
    }
    // ---- stage h0 -> bf16 swizzled LDS buf0 ----
    for (int idx = tid; idx < BC * 128; idx += NTH) {
        int bb = idx >> 7, d = idx & 127;
        const float* hp = &h0[(size_t)(b0 + bb) * HH + 2 * d];
        unsigned val = (unsigned)f2bf(hp[0]) | ((unsigned)f2bf(hp[1]) << 16);
        *(unsigned*)(hb[0] + bb * 512 + ((d * 4) ^ ((bb & 7) << 4))) = val;
    }
    if (tid < BC * 2) outacc[tid] = 0.f;

    // ---- c state: lane owns (batch lr, units 32w+16ch+4lg+r) ----
    float cc[2][4];
#pragma unroll
    for (int ch = 0; ch < 2; ++ch)
#pragma unroll
        for (int r = 0; r < 4; ++r)
            cc[ch][r] = c0[(size_t)(b0 + lr) * HH + 32 * w + 16 * ch + 4 * lg + r];

    // ---- W tiles (pre-scaled): tau = ch*4+gt; reg tau 0..5, LDS tau 6,7 ----
    short8 wfrag[48];
#pragma unroll
    for (int tau = 0; tau < 6; ++tau) {
        const int gt = tau & 3, ch = tau >> 2;
        const int row = 256 * gt + 32 * w + 16 * ch + lr;
        const float sc = SCL[gt];
#pragma unroll
        for (int s = 0; s < 8; ++s) {
            const float* p = &W_hh[(size_t)row * HH + 8 * lg + 32 * s];
            short8 f;
#pragma unroll
            for (int i = 0; i < 8; ++i) f[i] = (short)f2bf(sc * p[i]);
            wfrag[tau * 8 + s] = f;
        }
    }
#pragma unroll
    for (int i = 0; i < 48; ++i)
        asm volatile("" : "+v"(wfrag[i]));

#pragma unroll
    for (int ti = 0; ti < 2; ++ti) {                 // tau 6,7: ch=1, gt=2+ti
        const int gt = 2 + ti;
        const int row = 256 * gt + 32 * w + 16 + lr;
        const float sc = SCL[gt];
#pragma unroll
        for (int s = 0; s < 8; ++s) {
            const float* p = &W_hh[(size_t)row * HH + 8 * lg + 32 * s];
            short8 f;
#pragma unroll
            for (int i = 0; i < 8; ++i) f[i] = (short)f2bf(sc * p[i]);
            *(short8*)(WLDS + w * 16384 + ti * 8192 + s * 1024 + l * 16) = f;
        }
    }
    // ---- wxb (pre-scaled): per (w, tau, row=lr): lo16 = wx, hi16 = bias ----
#pragma unroll
    for (int tau = 0; tau < 8; ++tau) {
        const int gt = tau & 3, ch = tau >> 2;
        const int row = 256 * gt + 32 * w + 16 * ch + lr;
        const float sc = SCL[gt];
        if (lg == 0)
            wxb[w * 128 + tau * 16 + lr] =
                (unsigned)f2bf(sc * W_ih[row]) |
                ((unsigned)f2bf(sc * (b_ih[row] + b_hh[row])) << 16);
    }

    __syncthreads();

    const unsigned sw  = (unsigned)((lr & 7) << 4);
    const unsigned rdb = (unsigned)(lr * 512);
    const unsigned cwb = (unsigned)(64 * w + 8 * lg);   // write col base
    const char* wbase = WLDS + w * 16384 + l * 16;
    const float C2S = 2.88539008178f;                   // 2*log2e for tanh(c)
    float hv[2][4];

#pragma unroll 1
    for (int t = 0; t < TT; ++t) {
        const char* rb = hb[t & 1];
        char* wbp = hb[(t + 1) & 1];

        floatx4 acc[8] = {};

        // ---- K loop: r8 rhythm, 3 loads then 8 MFMAs per s ----
#pragma unroll
        for (int s = 0; s < 8; ++s) {
            short8 w6 = *(const short8*)(wbase + s * 1024);
            short8 w7 = *(const short8*)(wbase + 8192 + s * 1024);
            short8 bfr = *(const short8*)(rb + rdb +
                             (((unsigned)(16 * lg + 64 * s)) ^ sw));
#pragma unroll
            for (int tau = 0; tau < 6; ++tau)
                acc[tau] = __builtin_amdgcn_mfma_f32_16x16x32_bf16(
                               wfrag[tau * 8 + s], bfr, acc[tau], 0, 0, 0);
            acc[6] = __builtin_amdgcn_mfma_f32_16x16x32_bf16(
                         w6, bfr, acc[6], 0, 0, 0);
            acc[7] = __builtin_amdgcn_mfma_f32_16x16x32_bf16(
                         w7, bfr, acc[7], 0, 0, 0);
        }

        // ---- 9th K-step (r8 position): [wx | bias] x [x; 1] on lg==0 ----
        {
            unsigned xword = (lg == 0)
                ? ((0x3F80u << 16) | (unsigned)xw[t * BC + lr]) : 0u;
            short8 b8 = {(short)(xword & 0xFFFF), (short)(xword >> 16),
                         0, 0, 0, 0, 0, 0};
#pragma unroll
            for (int tau = 0; tau < 8; ++tau) {
                unsigned wv = (lg == 0) ? wxb[w * 128 + tau * 16 + lr] : 0u;
                short8 a8 = {(short)(wv & 0xFFFF), (short)(wv >> 16),
                             0, 0, 0, 0, 0, 0};
                acc[tau] = __builtin_amdgcn_mfma_f32_16x16x32_bf16(
                               a8, b8, acc[tau], 0, 0, 0);
            }
        }

        // ---- gates -> c,h (pre-scaled accs: bare v_exp) ----
#pragma unroll
        for (int ch = 0; ch < 2; ++ch) {
#pragma unroll
            for (int r = 0; r < 4; ++r) {
                float iv = sig2(acc[ch * 4 + 0][r]);
                float fv = sig2(acc[ch * 4 + 1][r]);
                float gv = tanh2(acc[ch * 4 + 2][r]);
                float ov = sig2(acc[ch * 4 + 3][r]);
                float c2 = fmaf(fv, cc[ch][r], iv * gv);
                cc[ch][r] = c2;
                hv[ch][r] = ov * tanh2(C2S * c2);
            }
            unsigned lo = (unsigned)f2bf(hv[ch][0]) |
                          ((unsigned)f2bf(hv[ch][1]) << 16);
            unsigned hi = (unsigned)f2bf(hv[ch][2]) |
                          ((unsigned)f2bf(hv[ch][3]) << 16);
            uint2 pk; pk.x = lo; pk.y = hi;
            *(uint2*)(wbp + rdb + (((unsigned)(cwb + 32 * ch)) ^ sw)) = pk;
        }

        __syncthreads();
    }

    // ---- epilogue: out = h_T @ W_fc^T + b_fc (block owns its batches) ----
    float p0 = 0.f, p1 = 0.f;
#pragma unroll
    for (int ch = 0; ch < 2; ++ch)
#pragma unroll
        for (int r = 0; r < 4; ++r) {
            const int u = 32 * w + 16 * ch + 4 * lg + r;
            p0 = fmaf(hv[ch][r], W_fc[u],      p0);
            p1 = fmaf(hv[ch][r], W_fc[HH + u], p1);
        }
    p0 += __shfl_xor(p0, 16, 64); p0 += __shfl_xor(p0, 32, 64);
    p1 += __shfl_xor(p1, 16, 64); p1 += __shfl_xor(p1, 32, 64);
    if (lg == 0) {
        atomicAdd(&outacc[lr * 2 + 0], p0);
        atomicAdd(&outacc[lr * 2 + 1], p1);
    }
    __syncthreads();
    if (tid < BC * 2) {
        int bb = tid >> 1, o = tid & 1;
        out[(size_t)(b0 + bb) * 2 + o] = outacc[tid] + b_fc[o];
    }
}

extern "C" void kernel_launch(void* const* d_in, const int* in_sizes, int n_in,
                              void* d_out, int out_size, void* d_ws, size_t ws_size,
                              hipStream_t stream) {
    const float* y_hist = (const float*)d_in[0];
    const float* h0     = (const float*)d_in[1];
    const float* c0     = (const float*)d_in[2];
    const float* W_ih   = (const float*)d_in[3];
    const float* W_hh   = (const float*)d_in[4];
    const float* b_ih   = (const float*)d_in[5];
    const float* b_hh   = (const float*)d_in[6];
    const float* W_fc   = (const float*)d_in[7];
    const float* b_fc   = (const float*)d_in[8];

    lstm_onecu<<<2048 / BC, NTH, 0, stream>>>(
        y_hist, h0, c0, W_ih, W_hh, b_ih, b_hh, W_fc, b_fc, (float*)d_out);
}